// Round 13
// baseline (1254.013 us; speedup 1.0000x reference)
//
#include <hip/hip_runtime.h>
#include <hip/hip_bf16.h>
#include <stdint.h>

// Problem constants
#define B_ROWS 32768
#define NUM_IN 1024
#define D_PAD2 1088   // 1064 padded to 17*64 K-tiles
#define HID    2048
#define NPAD   64     // 37 logits padded to 64

typedef __attribute__((ext_vector_type(8))) short bf16x8;
typedef __attribute__((ext_vector_type(4))) float f32x4;
typedef unsigned short ushort_t;

__device__ __forceinline__ unsigned short f2bf(float f){
  union { float f; uint32_t u; } x; x.f = f;
  uint32_t u = x.u;
  return (unsigned short)((u + 0x7FFFu + ((u >> 16) & 1u)) >> 16);
}

__device__ __forceinline__ float bf2f(unsigned short u){
  union { uint32_t u; float f; } x; x.u = ((uint32_t)u) << 16;
  return x.f;
}

__device__ __forceinline__ void gload16(const void* g, void* l){
  __builtin_amdgcn_global_load_lds((const __attribute__((address_space(1))) void*)g,
                                   (__attribute__((address_space(3))) void*)l, 16, 0, 0);
}

// ---------------- discretizer scan (per batch element) ----------------
__device__ __forceinline__ int disc_step(
    float cam0, float cam1, const int a[5],
    float& ac0, float& ac1, float& delta,
    int r[5], bool& dch, int& cam_steps, bool& committed, float& norm)
{
  const int RS[5] = {6, 8, 10, 11, 14};
  norm += committed ? 0.0f : 1.0f;
  bool commit = ((fabsf(cam0) < 1e-5f) && (fabsf(cam1) < 1e-5f)) || (cam_steps >= 6);
  #pragma unroll
  for (int i = 0; i < 5; ++i) commit = commit && (r[i] == a[i]);
  int dac = 0;
  bool modified = commit;
  #pragma unroll
  for (int i = 0; i < 5; ++i){
    bool disc = (!modified) && (r[i] != a[i]);
    if (disc){
      dac = (a[i] == 0) ? (r[i] - 1 + RS[i]) : (a[i] - 1 + RS[i]);
      r[i] = a[i];
      modified = true;
    }
  }
  float d2 = delta * 2.0f;
  // NOTE: reference compares BOTH cam0 and cam1 against ac[:,0] — replicate.
  bool dmask = (!modified) && (!dch) &&
               ((fabsf(cam0 - ac0) > d2) || (fabsf(cam1 - ac0) > d2));
  if (dmask){ dac = 5; delta = fminf(d2, 0.5f); modified = true; }
  if (!modified){
    float sx = (cam0 < ac0) ? -1.0f : 1.0f;
    float sy = (cam1 < ac1) ? -1.0f : 1.0f;
    dac = (sx < 0.0f) ? ((sy < 0.0f) ? 1 : 3) : ((sy < 0.0f) ? 2 : 4);
    ac0 += sx * delta; ac1 += sy * delta;
    delta *= 0.5f;
    dch = true;
    cam_steps += 1;
  }
  committed = committed || commit;
  return dac;
}

// ---------------- fused prep: fc convert (grid-stride) | W1^T | W2^T | disc ----------------
// block ranges: [0,2048) fc x8 ; [2048,2592) w1t-transpose ; [2592,3104) w2t ; [3104,3232) disc
__global__ void k_prep(const float* __restrict__ fc, const float* __restrict__ W1,
                       const float* __restrict__ W2,
                       const float* __restrict__ camera, const float* __restrict__ rand_u,
                       const int* __restrict__ afb, const int* __restrict__ alr,
                       const int* __restrict__ ajp, const int* __restrict__ ass,
                       const int* __restrict__ aat,
                       unsigned short* __restrict__ xb, unsigned short* __restrict__ w1t,
                       unsigned short* __restrict__ w2t, int* __restrict__ tgt)
{
  __shared__ float lt[64][65];      // transpose tile (+1 pad, conflict-free)
  const int b = blockIdx.x;
  const int tid = threadIdx.x;
  if (b < 2048){
    // fc f32 -> bf16, grid-stride over 16384 logical blocks (G11: cap grid, stride rest)
    #pragma unroll
    for (int it = 0; it < 8; ++it){
      int gid = (b + it * 2048) * 256 + tid;
      int row = gid >> 7;
      int c   = gid & 127;
      const float4* p = (const float4*)(fc + (size_t)row * NUM_IN + c * 8);
      float4 f0 = p[0], f1 = p[1];
      uint4 pk;
      pk.x = (uint32_t)f2bf(f0.x) | ((uint32_t)f2bf(f0.y) << 16);
      pk.y = (uint32_t)f2bf(f0.z) | ((uint32_t)f2bf(f0.w) << 16);
      pk.z = (uint32_t)f2bf(f1.x) | ((uint32_t)f2bf(f1.y) << 16);
      pk.w = (uint32_t)f2bf(f1.z) | ((uint32_t)f2bf(f1.w) << 16);
      *(uint4*)(xb + (size_t)row * D_PAD2 + c * 8) = pk;
    }
    return;
  }
  if (b < 2592){
    // W1 [1064][2048] -> w1t [2048][1088] via 64x64 LDS tile; coalesced both sides
    const int bi = b - 2048;
    const int kt = bi % 17, nt = bi / 17;
    const int k0 = kt * 64, n0 = nt * 64;
    const int c = tid & 63, rq = tid >> 6;
    #pragma unroll
    for (int rr = 0; rr < 16; ++rr){
      const int r = rr * 4 + rq;
      const int k = k0 + r;
      lt[r][c] = (k < 1064) ? W1[(size_t)k * HID + n0 + c] : 0.0f;
    }
    __syncthreads();
    #pragma unroll
    for (int rr = 0; rr < 16; ++rr){
      const int r = rr * 4 + rq;
      w1t[(size_t)(n0 + r) * D_PAD2 + k0 + c] = f2bf(lt[c][r]);
    }
    return;
  }
  if (b < 3104){
    int idx = (b - 2592) * 256 + tid;
    int n = idx >> 11;
    int k = idx & (HID - 1);
    float v = (n < 37) ? W2[(size_t)k * 37 + n] : 0.0f;
    w2t[idx] = f2bf(v);
    return;
  }
  // discretizer
  int row = (b - 3104) * 256 + tid;
  float cam0 = camera[2*row], cam1 = camera[2*row + 1];
  int a[5] = { afb[row], alr[row], ajp[row], ass[row], aat[row] };

  float ac0 = 0.f, ac1 = 0.f, delta = 0.0625f, norm = 0.f;
  int r[5] = {0,0,0,0,0};
  bool dch = false, committed = false; int cam_steps = 0;
  for (int t = 0; t < 20; ++t)
    disc_step(cam0, cam1, a, ac0, ac1, delta, r, dch, cam_steps, committed, norm);

  int rs = (int)(rand_u[row] * norm);
  if (rs > 19) rs = 19;
  if (rs < 0) rs = 0;

  ac0 = 0.f; ac1 = 0.f; delta = 0.0625f; norm = 0.f;
  r[0]=r[1]=r[2]=r[3]=r[4]=0; dch = false; committed = false; cam_steps = 0;
  for (int t = 0; t < rs; ++t)
    disc_step(cam0, cam1, a, ac0, ac1, delta, r, dch, cam_steps, committed, norm);

  float vec[40];
  #pragma unroll
  for (int j = 0; j < 40; ++j) vec[j] = 0.0f;
  vec[0] = ac0; vec[1] = ac1;
  const int offs[5] = {2, 5, 8, 10, 14};
  #pragma unroll
  for (int i = 0; i < 5; ++i) vec[offs[i] + r[i]] = 1.0f;
  vec[38] = delta; vec[39] = dch ? 1.0f : 0.0f;

  int dac = disc_step(cam0, cam1, a, ac0, ac1, delta, r, dch, cam_steps, committed, norm);
  tgt[row] = dac;

  unsigned short* o = xb + (size_t)row * D_PAD2 + NUM_IN;
  #pragma unroll
  for (int j = 0; j < 40; ++j) o[j] = f2bf(vec[j]);
  #pragma unroll
  for (int j = 40; j < 64; ++j) o[j] = 0;
}

// ---------------- GEMM1: 128x128 m97-structure, 4 waves, 5 blocks/CU + fused W2 ----------------
// LDS 32 KB: A [128][64] at ushort 0, B [128][64] at ushort 8192. Epilogue: h [128][128].

#define BAR() __syncthreads()

__global__ __launch_bounds__(256, 5) void k_gemm1(const ushort_t* __restrict__ xb,
                                                  const ushort_t* __restrict__ w1t,
                                                  const ushort_t* __restrict__ w2t,
                                                  const float* __restrict__ b1,
                                                  ushort_t* __restrict__ pbuf)
{
  __shared__ ushort_t lds[16384];   // 32 KiB
  const int t = threadIdx.x;        // 0..255
  const int lane = t & 63;
  const int wid = t >> 6;           // 4 waves: 2x2, wave tile 64x64
  const int wm = wid >> 1, wn = wid & 1;
  const int lr = lane & 15, lg = lane >> 4;

  // XCD-aware swizzle (nwg=4096, %8==0 -> bijective). 512 blocks/XCD chunk:
  // 32 row-tiles x 16 col-tiles -> A panel reused 16x within an XCD's L2.
  const int bid = blockIdx.x;
  const int swz = (bid & 7) * 512 + (bid >> 3);
  const int brow = (swz >> 4) << 7;   // 256 row tiles of 128
  const int bcol = (swz & 15) << 7;   // 16 col tiles of 128
  const int cb   = swz & 15;

  // fragment read bases (chunk XOR folded; rows are 64 ushort = 128 B)
  const int axor = lr & 7;
  const char* aBk[2];
  const char* bBk[2];
  aBk[0] = (const char*)lds + (wm*64 + lr)*128 + (((0 + lg) ^ axor) << 4);
  aBk[1] = (const char*)lds + (wm*64 + lr)*128 + (((4 + lg) ^ axor) << 4);
  bBk[0] = (const char*)lds + 16384 + (wn*64 + lr)*128 + (((0 + lg) ^ axor) << 4);
  bBk[1] = (const char*)lds + 16384 + (wn*64 + lr)*128 + (((4 + lg) ^ axor) << 4);

  f32x4 acc[4][4] = {};
  bf16x8 aR[4][2], bR[4][2];

  for (int kt = 0; kt < 17; ++kt){
    // stage A and B tiles into the single buffer (linear dest, pre-swizzled source)
    #pragma unroll
    for (int s = 0; s < 4; ++s){
      const int sr = s*32 + (t >> 3);
      const int sc = ((t & 7) ^ (sr & 7)) << 3;
      gload16(xb  + (size_t)(brow + sr) * D_PAD2 + (kt << 6) + sc, lds + s*2048 + t*8);
      gload16(w1t + (size_t)(bcol + sr) * D_PAD2 + (kt << 6) + sc, lds + 8192 + s*2048 + t*8);
    }
    BAR();   // compiler drains vmcnt(0) before s_barrier

    #pragma unroll
    for (int mi = 0; mi < 4; ++mi)
      #pragma unroll
      for (int kk = 0; kk < 2; ++kk)
        aR[mi][kk] = *(const bf16x8*)(aBk[kk] + mi*16*128);
    #pragma unroll
    for (int ni = 0; ni < 4; ++ni)
      #pragma unroll
      for (int kk = 0; kk < 2; ++kk)
        bR[ni][kk] = *(const bf16x8*)(bBk[kk] + ni*16*128);

    __builtin_amdgcn_s_setprio(1);
    #pragma unroll
    for (int mi = 0; mi < 4; ++mi)
      #pragma unroll
      for (int ni = 0; ni < 4; ++ni)
        #pragma unroll
        for (int kk = 0; kk < 2; ++kk)
          acc[mi][ni] = __builtin_amdgcn_mfma_f32_16x16x32_bf16(
              aR[mi][kk], bR[ni][kk], acc[mi][ni], 0, 0, 0);
    __builtin_amdgcn_s_setprio(0);
    BAR();   // protect LDS from next iteration's staging
  }

  // ---- fused epilogue: silu -> LDS h-tile [128][128] -> mini-GEMM vs W2 chunk ----
  float b1v[4];
  #pragma unroll
  for (int ni = 0; ni < 4; ++ni) b1v[ni] = b1[bcol + wn*64 + ni*16 + lr];

  #pragma unroll
  for (int mi = 0; mi < 4; ++mi){
    #pragma unroll
    for (int ni = 0; ni < 4; ++ni){
      const int col = wn*64 + ni*16 + lr;
      #pragma unroll
      for (int i2 = 0; i2 < 4; ++i2){
        const int row = wm*64 + mi*16 + lg*4 + i2;
        float v = acc[mi][ni][i2] + b1v[ni];
        float s = v / (1.0f + __expf(-v));     // silu
        const int c = col >> 3;                 // 0..15
        lds[row*128 + ((c ^ (row & 7)) << 3) + (col & 7)] = f2bf(s);
      }
    }
  }
  BAR();

  // W2 fragments for this block's 128 k-cols (K=128 -> 4 ks steps)
  bf16x8 w2f[4][4];
  #pragma unroll
  for (int ks = 0; ks < 4; ++ks)
    #pragma unroll
    for (int ni = 0; ni < 4; ++ni)
      w2f[ks][ni] = *(const bf16x8*)(w2t + (size_t)(ni*16 + lr) * HID + bcol + ks*32 + lg*8);

  // mini-GEMM: partial[r][n] = hTile[r][:128] @ W2chunk[:128][n], n in [0,64)
  const int rb = wid * 32;
  f32x4 acc2[2][4] = {};
  #pragma unroll
  for (int ks = 0; ks < 4; ++ks){
    bf16x8 a2[2];
    #pragma unroll
    for (int m = 0; m < 2; ++m){
      const int row = rb + m*16 + lr;
      const int c = ks*4 + lg;
      a2[m] = *(const bf16x8*)(lds + row*128 + ((c ^ (row & 7)) << 3));
    }
    #pragma unroll
    for (int m = 0; m < 2; ++m)
      #pragma unroll
      for (int ni = 0; ni < 4; ++ni)
        acc2[m][ni] = __builtin_amdgcn_mfma_f32_16x16x32_bf16(
            a2[m], w2f[ks][ni], acc2[m][ni], 0, 0, 0);
  }

  // store bf16 partials: pbuf[cb][row][col]  (rows contiguous 128 B)
  #pragma unroll
  for (int m = 0; m < 2; ++m)
    #pragma unroll
    for (int ni = 0; ni < 4; ++ni)
      #pragma unroll
      for (int i2 = 0; i2 < 4; ++i2){
        const int r = brow + rb + m*16 + lg*4 + i2;
        pbuf[((size_t)cb << 21) + ((size_t)r << 6) + ni*16 + lr] = f2bf(acc2[m][ni][i2]);
      }
}

// ---------------- reduce: sum 16 bf16 partials + b2 -> log-softmax -> NLL ----------------
__global__ __launch_bounds__(256) void k_red(const ushort_t* __restrict__ pbuf,
                                             const float* __restrict__ b2,
                                             const int* __restrict__ tgt,
                                             float* __restrict__ loss)
{
  const int lane = threadIdx.x & 63, w = threadIdx.x >> 6;
  const int row0 = blockIdx.x * 128 + w * 32;
  const float bias = (lane < 37) ? b2[lane] : 0.0f;
  for (int i = 0; i < 32; ++i){
    const int r = row0 + i;
    float s = 0.0f;
    #pragma unroll
    for (int cbk = 0; cbk < 16; ++cbk)
      s += bf2f(pbuf[((size_t)cbk << 21) + ((size_t)r << 6) + lane]);
    float x = (lane < 37) ? (s + bias) : -1e30f;
    float m = x;
    #pragma unroll
    for (int off = 1; off < 64; off <<= 1) m = fmaxf(m, __shfl_xor(m, off, 64));
    float e = __expf(x - m);
    float se = e;
    #pragma unroll
    for (int off = 1; off < 64; off <<= 1) se += __shfl_xor(se, off, 64);
    const int tg = tgt[r];
    const float pick = __shfl(x, tg, 64);
    if (lane == 0) loss[r] = m + __logf(se) - pick;
  }
}

// ---------------- launch ----------------
extern "C" void kernel_launch(void* const* d_in, const int* in_sizes, int n_in,
                              void* d_out, int out_size, void* d_ws, size_t ws_size,
                              hipStream_t stream)
{
  (void)in_sizes; (void)n_in; (void)out_size; (void)ws_size;
  const float* fc  = (const float*)d_in[0];
  const float* cam = (const float*)d_in[1];
  const float* ru  = (const float*)d_in[2];
  const float* W1  = (const float*)d_in[3];
  const float* b1  = (const float*)d_in[4];
  const float* W2  = (const float*)d_in[5];
  const float* b2  = (const float*)d_in[6];
  const int* afb = (const int*)d_in[7];
  const int* alr = (const int*)d_in[8];
  const int* ajp = (const int*)d_in[9];
  const int* ass = (const int*)d_in[10];
  const int* aat = (const int*)d_in[11];
  float* loss = (float*)d_out;

  // workspace layout (bytes):
  // xb   : 32768 x 1088 bf16   = 71,303,168
  // w1t  : 2048 x 1088 bf16    =  4,456,448
  // w2t  : 64 x 2048 bf16      =    262,144
  // tgt  : 32768 int32         =    131,072
  // pbuf : 16 x 32768 x 64 bf16= 67,108,864   (total ~136.6 MiB)
  char* ws = (char*)d_ws;
  unsigned short* xb  = (unsigned short*)(ws);
  unsigned short* w1t = (unsigned short*)(ws + 71303168);
  unsigned short* w2t = (unsigned short*)(ws + 75759616);
  int*            tgt = (int*)           (ws + 76021760);
  unsigned short* pbuf= (unsigned short*)(ws + 76152832);

  // fused prep: fc(2048 x8 grid-stride) + w1t-transpose(544) + w2t(512) + disc(128)
  k_prep<<<3232, 256, 0, stream>>>(fc, W1, W2, cam, ru, afb, alr, ajp, ass, aat,
                                   xb, w1t, w2t, tgt);
  k_gemm1<<<(B_ROWS/128) * (HID/128), 256, 0, stream>>>(xb, w1t, w2t, b1, pbuf);
  k_red  <<<B_ROWS / 128, 256, 0, stream>>>(pbuf, b2, tgt, loss);
}

// Round 14
// 256.708 us; speedup vs baseline: 4.8850x; 4.8850x over previous
//
#include <hip/hip_runtime.h>
#include <hip/hip_bf16.h>
#include <stdint.h>

// Problem constants
#define B_ROWS 32768
#define NUM_IN 1024
#define D_PAD2 1088   // 1064 padded to 17*64 K-tiles
#define HID    2048
#define NPAD   64     // 37 logits padded to 64

typedef __attribute__((ext_vector_type(8))) short bf16x8;
typedef __attribute__((ext_vector_type(4))) float f32x4;
typedef unsigned short ushort_t;

__device__ __forceinline__ unsigned short f2bf(float f){
  union { float f; uint32_t u; } x; x.f = f;
  uint32_t u = x.u;
  return (unsigned short)((u + 0x7FFFu + ((u >> 16) & 1u)) >> 16);
}

__device__ __forceinline__ float bf2f(unsigned short u){
  union { uint32_t u; float f; } x; x.u = ((uint32_t)u) << 16;
  return x.f;
}

__device__ __forceinline__ void gload16(const void* g, void* l){
  __builtin_amdgcn_global_load_lds((const __attribute__((address_space(1))) void*)g,
                                   (__attribute__((address_space(3))) void*)l, 16, 0, 0);
}

// ---------------- discretizer scan (per batch element) ----------------
__device__ __forceinline__ int disc_step(
    float cam0, float cam1, const int a[5],
    float& ac0, float& ac1, float& delta,
    int r[5], bool& dch, int& cam_steps, bool& committed, float& norm)
{
  const int RS[5] = {6, 8, 10, 11, 14};
  norm += committed ? 0.0f : 1.0f;
  bool commit = ((fabsf(cam0) < 1e-5f) && (fabsf(cam1) < 1e-5f)) || (cam_steps >= 6);
  #pragma unroll
  for (int i = 0; i < 5; ++i) commit = commit && (r[i] == a[i]);
  int dac = 0;
  bool modified = commit;
  #pragma unroll
  for (int i = 0; i < 5; ++i){
    bool disc = (!modified) && (r[i] != a[i]);
    if (disc){
      dac = (a[i] == 0) ? (r[i] - 1 + RS[i]) : (a[i] - 1 + RS[i]);
      r[i] = a[i];
      modified = true;
    }
  }
  float d2 = delta * 2.0f;
  // NOTE: reference compares BOTH cam0 and cam1 against ac[:,0] — replicate.
  bool dmask = (!modified) && (!dch) &&
               ((fabsf(cam0 - ac0) > d2) || (fabsf(cam1 - ac0) > d2));
  if (dmask){ dac = 5; delta = fminf(d2, 0.5f); modified = true; }
  if (!modified){
    float sx = (cam0 < ac0) ? -1.0f : 1.0f;
    float sy = (cam1 < ac1) ? -1.0f : 1.0f;
    dac = (sx < 0.0f) ? ((sy < 0.0f) ? 1 : 3) : ((sy < 0.0f) ? 2 : 4);
    ac0 += sx * delta; ac1 += sy * delta;
    delta *= 0.5f;
    dch = true;
    cam_steps += 1;
  }
  committed = committed || commit;
  return dac;
}

// ---------------- fused prep: fc convert (grid-stride) | W1^T | W2^T | disc ----------------
// block ranges: [0,2048) fc x8 ; [2048,2592) w1t-transpose ; [2592,3104) w2t ; [3104,3232) disc
__global__ void k_prep(const float* __restrict__ fc, const float* __restrict__ W1,
                       const float* __restrict__ W2,
                       const float* __restrict__ camera, const float* __restrict__ rand_u,
                       const int* __restrict__ afb, const int* __restrict__ alr,
                       const int* __restrict__ ajp, const int* __restrict__ ass,
                       const int* __restrict__ aat,
                       unsigned short* __restrict__ xb, unsigned short* __restrict__ w1t,
                       unsigned short* __restrict__ w2t, int* __restrict__ tgt)
{
  __shared__ float lt[64][65];      // transpose tile (+1 pad, conflict-free)
  const int b = blockIdx.x;
  const int tid = threadIdx.x;
  if (b < 2048){
    // fc f32 -> bf16, grid-stride over 16384 logical blocks
    #pragma unroll
    for (int it = 0; it < 8; ++it){
      int gid = (b + it * 2048) * 256 + tid;
      int row = gid >> 7;
      int c   = gid & 127;
      const float4* p = (const float4*)(fc + (size_t)row * NUM_IN + c * 8);
      float4 f0 = p[0], f1 = p[1];
      uint4 pk;
      pk.x = (uint32_t)f2bf(f0.x) | ((uint32_t)f2bf(f0.y) << 16);
      pk.y = (uint32_t)f2bf(f0.z) | ((uint32_t)f2bf(f0.w) << 16);
      pk.z = (uint32_t)f2bf(f1.x) | ((uint32_t)f2bf(f1.y) << 16);
      pk.w = (uint32_t)f2bf(f1.z) | ((uint32_t)f2bf(f1.w) << 16);
      *(uint4*)(xb + (size_t)row * D_PAD2 + c * 8) = pk;
    }
    return;
  }
  if (b < 2592){
    // W1 [1064][2048] -> w1t [2048][1088] via 64x64 LDS tile; coalesced both sides
    const int bi = b - 2048;
    const int kt = bi % 17, nt = bi / 17;
    const int k0 = kt * 64, n0 = nt * 64;
    const int c = tid & 63, rq = tid >> 6;
    #pragma unroll
    for (int rr = 0; rr < 16; ++rr){
      const int r = rr * 4 + rq;
      const int k = k0 + r;
      lt[r][c] = (k < 1064) ? W1[(size_t)k * HID + n0 + c] : 0.0f;
    }
    __syncthreads();
    #pragma unroll
    for (int rr = 0; rr < 16; ++rr){
      const int r = rr * 4 + rq;
      w1t[(size_t)(n0 + r) * D_PAD2 + k0 + c] = f2bf(lt[c][r]);
    }
    return;
  }
  if (b < 3104){
    int idx = (b - 2592) * 256 + tid;
    int n = idx >> 11;
    int k = idx & (HID - 1);
    float v = (n < 37) ? W2[(size_t)k * 37 + n] : 0.0f;
    w2t[idx] = f2bf(v);
    return;
  }
  // discretizer
  int row = (b - 3104) * 256 + tid;
  float cam0 = camera[2*row], cam1 = camera[2*row + 1];
  int a[5] = { afb[row], alr[row], ajp[row], ass[row], aat[row] };

  float ac0 = 0.f, ac1 = 0.f, delta = 0.0625f, norm = 0.f;
  int r[5] = {0,0,0,0,0};
  bool dch = false, committed = false; int cam_steps = 0;
  for (int t = 0; t < 20; ++t)
    disc_step(cam0, cam1, a, ac0, ac1, delta, r, dch, cam_steps, committed, norm);

  int rs = (int)(rand_u[row] * norm);
  if (rs > 19) rs = 19;
  if (rs < 0) rs = 0;

  ac0 = 0.f; ac1 = 0.f; delta = 0.0625f; norm = 0.f;
  r[0]=r[1]=r[2]=r[3]=r[4]=0; dch = false; committed = false; cam_steps = 0;
  for (int t = 0; t < rs; ++t)
    disc_step(cam0, cam1, a, ac0, ac1, delta, r, dch, cam_steps, committed, norm);

  float vec[40];
  #pragma unroll
  for (int j = 0; j < 40; ++j) vec[j] = 0.0f;
  vec[0] = ac0; vec[1] = ac1;
  const int offs[5] = {2, 5, 8, 10, 14};
  #pragma unroll
  for (int i = 0; i < 5; ++i) vec[offs[i] + r[i]] = 1.0f;
  vec[38] = delta; vec[39] = dch ? 1.0f : 0.0f;

  int dac = disc_step(cam0, cam1, a, ac0, ac1, delta, r, dch, cam_steps, committed, norm);
  tgt[row] = dac;

  unsigned short* o = xb + (size_t)row * D_PAD2 + NUM_IN;
  #pragma unroll
  for (int j = 0; j < 40; ++j) o[j] = f2bf(vec[j]);
  #pragma unroll
  for (int j = 40; j < 64; ++j) o[j] = 0;
}

// ---------------- GEMM1: 128x128, 4 waves, 4 blocks/CU (kk-split frags) + fused W2 ----------------
// LDS 32 KB: A [128][64] at ushort 0, B [128][64] at ushort 8192. Epilogue: h [128][128].
// Register budget @4 waves/SIMD = 128/wave unified: acc 64 (AGPR) + frags 32 + addr ~20.

#define BAR() __syncthreads()

__global__ __launch_bounds__(256, 4) void k_gemm1(const ushort_t* __restrict__ xb,
                                                  const ushort_t* __restrict__ w1t,
                                                  const ushort_t* __restrict__ w2t,
                                                  const float* __restrict__ b1,
                                                  ushort_t* __restrict__ pbuf)
{
  __shared__ ushort_t lds[16384];   // 32 KiB
  const int t = threadIdx.x;        // 0..255
  const int lane = t & 63;
  const int wid = t >> 6;           // 4 waves: 2x2, wave tile 64x64
  const int wm = wid >> 1, wn = wid & 1;
  const int lr = lane & 15, lg = lane >> 4;

  // XCD-aware swizzle (nwg=4096, %8==0 -> bijective). 512 blocks/XCD chunk.
  const int bid = blockIdx.x;
  const int swz = (bid & 7) * 512 + (bid >> 3);
  const int brow = (swz >> 4) << 7;   // 256 row tiles of 128
  const int bcol = (swz & 15) << 7;   // 16 col tiles of 128
  const int cb   = swz & 15;

  // fragment read bases (chunk XOR folded; rows are 64 ushort = 128 B)
  const int axor = lr & 7;
  const char* aBk[2];
  const char* bBk[2];
  aBk[0] = (const char*)lds + (wm*64 + lr)*128 + (((0 + lg) ^ axor) << 4);
  aBk[1] = (const char*)lds + (wm*64 + lr)*128 + (((4 + lg) ^ axor) << 4);
  bBk[0] = (const char*)lds + 16384 + (wn*64 + lr)*128 + (((0 + lg) ^ axor) << 4);
  bBk[1] = (const char*)lds + 16384 + (wn*64 + lr)*128 + (((4 + lg) ^ axor) << 4);

  f32x4 acc[4][4] = {};

  for (int kt = 0; kt < 17; ++kt){
    // stage A and B tiles into the single buffer (linear dest, pre-swizzled source)
    #pragma unroll
    for (int s = 0; s < 4; ++s){
      const int sr = s*32 + (t >> 3);
      const int sc = ((t & 7) ^ (sr & 7)) << 3;
      gload16(xb  + (size_t)(brow + sr) * D_PAD2 + (kt << 6) + sc, lds + s*2048 + t*8);
      gload16(w1t + (size_t)(bcol + sr) * D_PAD2 + (kt << 6) + sc, lds + 8192 + s*2048 + t*8);
    }
    BAR();   // compiler drains vmcnt(0) before s_barrier

    // kk-split: one 32-reg fragment bank reused for both K-halves.
    #pragma unroll
    for (int kk = 0; kk < 2; ++kk){
      bf16x8 aR[4], bR[4];
      #pragma unroll
      for (int mi = 0; mi < 4; ++mi) aR[mi] = *(const bf16x8*)(aBk[kk] + mi*2048);
      #pragma unroll
      for (int ni = 0; ni < 4; ++ni) bR[ni] = *(const bf16x8*)(bBk[kk] + ni*2048);

      __builtin_amdgcn_s_setprio(1);
      #pragma unroll
      for (int mi = 0; mi < 4; ++mi)
        #pragma unroll
        for (int ni = 0; ni < 4; ++ni)
          acc[mi][ni] = __builtin_amdgcn_mfma_f32_16x16x32_bf16(
              aR[mi], bR[ni], acc[mi][ni], 0, 0, 0);
      __builtin_amdgcn_s_setprio(0);
    }
    BAR();   // protect LDS from next iteration's staging
  }

  // ---- fused epilogue: silu -> LDS h-tile [128][128] -> mini-GEMM vs W2 chunk ----
  float b1v[4];
  #pragma unroll
  for (int ni = 0; ni < 4; ++ni) b1v[ni] = b1[bcol + wn*64 + ni*16 + lr];

  #pragma unroll
  for (int mi = 0; mi < 4; ++mi){
    #pragma unroll
    for (int ni = 0; ni < 4; ++ni){
      const int col = wn*64 + ni*16 + lr;
      #pragma unroll
      for (int i2 = 0; i2 < 4; ++i2){
        const int row = wm*64 + mi*16 + lg*4 + i2;
        float v = acc[mi][ni][i2] + b1v[ni];
        float s = v / (1.0f + __expf(-v));     // silu
        const int c = col >> 3;                 // 0..15
        lds[row*128 + ((c ^ (row & 7)) << 3) + (col & 7)] = f2bf(s);
      }
    }
  }
  BAR();

  // mini-GEMM: partial[r][n] = hTile[r][:128] @ W2chunk[:128][n], n in [0,64)
  // W2 fragments in two [2][4] batches (32 regs each) to respect the 128-reg budget.
  const int rb = wid * 32;
  f32x4 acc2[2][4] = {};
  #pragma unroll
  for (int half = 0; half < 2; ++half){
    bf16x8 w2f[2][4];
    #pragma unroll
    for (int ks = 0; ks < 2; ++ks)
      #pragma unroll
      for (int ni = 0; ni < 4; ++ni)
        w2f[ks][ni] = *(const bf16x8*)(w2t + (size_t)(ni*16 + lr) * HID + bcol + (half*2+ks)*32 + lg*8);
    #pragma unroll
    for (int ks = 0; ks < 2; ++ks){
      const int kss = half*2 + ks;
      bf16x8 a2[2];
      #pragma unroll
      for (int m = 0; m < 2; ++m){
        const int row = rb + m*16 + lr;
        const int c = kss*4 + lg;
        a2[m] = *(const bf16x8*)(lds + row*128 + ((c ^ (row & 7)) << 3));
      }
      #pragma unroll
      for (int m = 0; m < 2; ++m)
        #pragma unroll
        for (int ni = 0; ni < 4; ++ni)
          acc2[m][ni] = __builtin_amdgcn_mfma_f32_16x16x32_bf16(
              a2[m], w2f[ks][ni], acc2[m][ni], 0, 0, 0);
    }
  }

  // store bf16 partials: pbuf[cb][row][col]  (rows contiguous 128 B)
  #pragma unroll
  for (int m = 0; m < 2; ++m)
    #pragma unroll
    for (int ni = 0; ni < 4; ++ni)
      #pragma unroll
      for (int i2 = 0; i2 < 4; ++i2){
        const int r = brow + rb + m*16 + lg*4 + i2;
        pbuf[((size_t)cb << 21) + ((size_t)r << 6) + ni*16 + lr] = f2bf(acc2[m][ni][i2]);
      }
}

// ---------------- reduce: sum 16 bf16 partials + b2 -> log-softmax -> NLL ----------------
__global__ __launch_bounds__(256) void k_red(const ushort_t* __restrict__ pbuf,
                                             const float* __restrict__ b2,
                                             const int* __restrict__ tgt,
                                             float* __restrict__ loss)
{
  const int lane = threadIdx.x & 63, w = threadIdx.x >> 6;
  const int row0 = blockIdx.x * 128 + w * 32;
  const float bias = (lane < 37) ? b2[lane] : 0.0f;
  for (int i = 0; i < 32; ++i){
    const int r = row0 + i;
    float s = 0.0f;
    #pragma unroll
    for (int cbk = 0; cbk < 16; ++cbk)
      s += bf2f(pbuf[((size_t)cbk << 21) + ((size_t)r << 6) + lane]);
    float x = (lane < 37) ? (s + bias) : -1e30f;
    float m = x;
    #pragma unroll
    for (int off = 1; off < 64; off <<= 1) m = fmaxf(m, __shfl_xor(m, off, 64));
    float e = __expf(x - m);
    float se = e;
    #pragma unroll
    for (int off = 1; off < 64; off <<= 1) se += __shfl_xor(se, off, 64);
    const int tg = tgt[r];
    const float pick = __shfl(x, tg, 64);
    if (lane == 0) loss[r] = m + __logf(se) - pick;
  }
}

// ---------------- launch ----------------
extern "C" void kernel_launch(void* const* d_in, const int* in_sizes, int n_in,
                              void* d_out, int out_size, void* d_ws, size_t ws_size,
                              hipStream_t stream)
{
  (void)in_sizes; (void)n_in; (void)out_size; (void)ws_size;
  const float* fc  = (const float*)d_in[0];
  const float* cam = (const float*)d_in[1];
  const float* ru  = (const float*)d_in[2];
  const float* W1  = (const float*)d_in[3];
  const float* b1  = (const float*)d_in[4];
  const float* W2  = (const float*)d_in[5];
  const float* b2  = (const float*)d_in[6];
  const int* afb = (const int*)d_in[7];
  const int* alr = (const int*)d_in[8];
  const int* ajp = (const int*)d_in[9];
  const int* ass = (const int*)d_in[10];
  const int* aat = (const int*)d_in[11];
  float* loss = (float*)d_out;

  // workspace layout (bytes):
  // xb   : 32768 x 1088 bf16   = 71,303,168
  // w1t  : 2048 x 1088 bf16    =  4,456,448
  // w2t  : 64 x 2048 bf16      =    262,144
  // tgt  : 32768 int32         =    131,072
  // pbuf : 16 x 32768 x 64 bf16= 67,108,864   (total ~136.6 MiB)
  char* ws = (char*)d_ws;
  unsigned short* xb  = (unsigned short*)(ws);
  unsigned short* w1t = (unsigned short*)(ws + 71303168);
  unsigned short* w2t = (unsigned short*)(ws + 75759616);
  int*            tgt = (int*)           (ws + 76021760);
  unsigned short* pbuf= (unsigned short*)(ws + 76152832);

  // fused prep: fc(2048 x8 grid-stride) + w1t-transpose(544) + w2t(512) + disc(128)
  k_prep<<<3232, 256, 0, stream>>>(fc, W1, W2, cam, ru, afb, alr, ajp, ass, aat,
                                   xb, w1t, w2t, tgt);
  k_gemm1<<<(B_ROWS/128) * (HID/128), 256, 0, stream>>>(xb, w1t, w2t, b1, pbuf);
  k_red  <<<B_ROWS / 128, 256, 0, stream>>>(pbuf, b2, tgt, loss);
}

// Round 16
// 253.507 us; speedup vs baseline: 4.9467x; 1.0126x over previous
//
#include <hip/hip_runtime.h>
#include <hip/hip_bf16.h>
#include <stdint.h>

// Problem constants
#define B_ROWS 32768
#define NUM_IN 1024
#define D_PAD2 1088   // 1064 padded to 17*64 K-tiles
#define HID    2048
#define NPAD   64     // 37 logits padded to 64

typedef __attribute__((ext_vector_type(8))) short bf16x8;
typedef __attribute__((ext_vector_type(4))) float f32x4;
typedef unsigned short ushort_t;

__device__ __forceinline__ unsigned short f2bf(float f){
  union { float f; uint32_t u; } x; x.f = f;
  uint32_t u = x.u;
  return (unsigned short)((u + 0x7FFFu + ((u >> 16) & 1u)) >> 16);
}

__device__ __forceinline__ float bf2f(unsigned short u){
  union { uint32_t u; float f; } x; x.u = ((uint32_t)u) << 16;
  return x.f;
}

// ---------------- discretizer scan (per batch element) ----------------
__device__ __forceinline__ int disc_step(
    float cam0, float cam1, const int a[5],
    float& ac0, float& ac1, float& delta,
    int r[5], bool& dch, int& cam_steps, bool& committed, float& norm)
{
  const int RS[5] = {6, 8, 10, 11, 14};
  norm += committed ? 0.0f : 1.0f;
  bool commit = ((fabsf(cam0) < 1e-5f) && (fabsf(cam1) < 1e-5f)) || (cam_steps >= 6);
  #pragma unroll
  for (int i = 0; i < 5; ++i) commit = commit && (r[i] == a[i]);
  int dac = 0;
  bool modified = commit;
  #pragma unroll
  for (int i = 0; i < 5; ++i){
    bool disc = (!modified) && (r[i] != a[i]);
    if (disc){
      dac = (a[i] == 0) ? (r[i] - 1 + RS[i]) : (a[i] - 1 + RS[i]);
      r[i] = a[i];
      modified = true;
    }
  }
  float d2 = delta * 2.0f;
  // NOTE: reference compares BOTH cam0 and cam1 against ac[:,0] — replicate.
  bool dmask = (!modified) && (!dch) &&
               ((fabsf(cam0 - ac0) > d2) || (fabsf(cam1 - ac0) > d2));
  if (dmask){ dac = 5; delta = fminf(d2, 0.5f); modified = true; }
  if (!modified){
    float sx = (cam0 < ac0) ? -1.0f : 1.0f;
    float sy = (cam1 < ac1) ? -1.0f : 1.0f;
    dac = (sx < 0.0f) ? ((sy < 0.0f) ? 1 : 3) : ((sy < 0.0f) ? 2 : 4);
    ac0 += sx * delta; ac1 += sy * delta;
    delta *= 0.5f;
    dch = true;
    cam_steps += 1;
  }
  committed = committed || commit;
  return dac;
}

// ---------------- fused prep: fc convert (grid-stride) | W1^T | W2^T | disc ----------------
// block ranges: [0,2048) fc x8 ; [2048,2592) w1t-transpose ; [2592,3104) w2t ; [3104,3232) disc
__global__ void k_prep(const float* __restrict__ fc, const float* __restrict__ W1,
                       const float* __restrict__ W2,
                       const float* __restrict__ camera, const float* __restrict__ rand_u,
                       const int* __restrict__ afb, const int* __restrict__ alr,
                       const int* __restrict__ ajp, const int* __restrict__ ass,
                       const int* __restrict__ aat,
                       unsigned short* __restrict__ xb, unsigned short* __restrict__ w1t,
                       unsigned short* __restrict__ w2t, int* __restrict__ tgt)
{
  __shared__ float lt[64][65];      // transpose tile (+1 pad, conflict-free)
  const int b = blockIdx.x;
  const int tid = threadIdx.x;
  if (b < 2048){
    // fc f32 -> bf16, grid-stride over 16384 logical blocks
    #pragma unroll
    for (int it = 0; it < 8; ++it){
      int gid = (b + it * 2048) * 256 + tid;
      int row = gid >> 7;
      int c   = gid & 127;
      const float4* p = (const float4*)(fc + (size_t)row * NUM_IN + c * 8);
      float4 f0 = p[0], f1 = p[1];
      uint4 pk;
      pk.x = (uint32_t)f2bf(f0.x) | ((uint32_t)f2bf(f0.y) << 16);
      pk.y = (uint32_t)f2bf(f0.z) | ((uint32_t)f2bf(f0.w) << 16);
      pk.z = (uint32_t)f2bf(f1.x) | ((uint32_t)f2bf(f1.y) << 16);
      pk.w = (uint32_t)f2bf(f1.z) | ((uint32_t)f2bf(f1.w) << 16);
      *(uint4*)(xb + (size_t)row * D_PAD2 + c * 8) = pk;
    }
    return;
  }
  if (b < 2592){
    // W1 [1064][2048] -> w1t [2048][1088] via 64x64 LDS tile; coalesced both sides
    const int bi = b - 2048;
    const int kt = bi % 17, nt = bi / 17;
    const int k0 = kt * 64, n0 = nt * 64;
    const int c = tid & 63, rq = tid >> 6;
    #pragma unroll
    for (int rr = 0; rr < 16; ++rr){
      const int r = rr * 4 + rq;
      const int k = k0 + r;
      lt[r][c] = (k < 1064) ? W1[(size_t)k * HID + n0 + c] : 0.0f;
    }
    __syncthreads();
    #pragma unroll
    for (int rr = 0; rr < 16; ++rr){
      const int r = rr * 4 + rq;
      w1t[(size_t)(n0 + r) * D_PAD2 + k0 + c] = f2bf(lt[c][r]);
    }
    return;
  }
  if (b < 3104){
    int idx = (b - 2592) * 256 + tid;
    int n = idx >> 11;
    int k = idx & (HID - 1);
    float v = (n < 37) ? W2[(size_t)k * 37 + n] : 0.0f;
    w2t[idx] = f2bf(v);
    return;
  }
  // discretizer
  int row = (b - 3104) * 256 + tid;
  float cam0 = camera[2*row], cam1 = camera[2*row + 1];
  int a[5] = { afb[row], alr[row], ajp[row], ass[row], aat[row] };

  float ac0 = 0.f, ac1 = 0.f, delta = 0.0625f, norm = 0.f;
  int r[5] = {0,0,0,0,0};
  bool dch = false, committed = false; int cam_steps = 0;
  for (int t = 0; t < 20; ++t)
    disc_step(cam0, cam1, a, ac0, ac1, delta, r, dch, cam_steps, committed, norm);

  int rs = (int)(rand_u[row] * norm);
  if (rs > 19) rs = 19;
  if (rs < 0) rs = 0;

  ac0 = 0.f; ac1 = 0.f; delta = 0.0625f; norm = 0.f;
  r[0]=r[1]=r[2]=r[3]=r[4]=0; dch = false; committed = false; cam_steps = 0;
  for (int t = 0; t < rs; ++t)
    disc_step(cam0, cam1, a, ac0, ac1, delta, r, dch, cam_steps, committed, norm);

  float vec[40];
  #pragma unroll
  for (int j = 0; j < 40; ++j) vec[j] = 0.0f;
  vec[0] = ac0; vec[1] = ac1;
  const int offs[5] = {2, 5, 8, 10, 14};
  #pragma unroll
  for (int i = 0; i < 5; ++i) vec[offs[i] + r[i]] = 1.0f;
  vec[38] = delta; vec[39] = dch ? 1.0f : 0.0f;

  int dac = disc_step(cam0, cam1, a, ac0, ac1, delta, r, dch, cam_steps, committed, norm);
  tgt[row] = dac;

  unsigned short* o = xb + (size_t)row * D_PAD2 + NUM_IN;
  #pragma unroll
  for (int j = 0; j < 40; ++j) o[j] = f2bf(vec[j]);
  #pragma unroll
  for (int j = 40; j < 64; ++j) o[j] = 0;
}

// ---------------- GEMM1: 128x128, 4 waves, 4 blocks/CU, unrolled K (compiler-folded imm) ----------------
// LDS 32 KB: A [128][64] at ushort 0, B [128][64] at ushort 8192. Epilogue: h [128][128].
// Staging: invariant base pointers + compile-time constant displacement (KT*64 ushorts);
// builtin offset arg ALWAYS 0 (round-15 lesson: nonzero offset arg corrupts staging).

#define BAR() __syncthreads()

#define GL16(G, L) __builtin_amdgcn_global_load_lds( \
    (const __attribute__((address_space(1))) void*)(G), \
    (__attribute__((address_space(3))) void*)(L), 16, 0, 0)

// one K-step: stage tile KT (A+B, 8 loads, const-folded displacement), sync,
// kk-split frags + 32 MFMA, sync
#define KSTEP(KT) do { \
    GL16(gA[0] + (KT)*64, lA0); GL16(gA[1] + (KT)*64, lA1); \
    GL16(gA[2] + (KT)*64, lA2); GL16(gA[3] + (KT)*64, lA3); \
    GL16(gB[0] + (KT)*64, lB0); GL16(gB[1] + (KT)*64, lB1); \
    GL16(gB[2] + (KT)*64, lB2); GL16(gB[3] + (KT)*64, lB3); \
    BAR(); \
    _Pragma("unroll") \
    for (int kk = 0; kk < 2; ++kk){ \
      bf16x8 aR[4], bR[4]; \
      _Pragma("unroll") \
      for (int mi = 0; mi < 4; ++mi) aR[mi] = *(const bf16x8*)(aBk[kk] + mi*2048); \
      _Pragma("unroll") \
      for (int ni = 0; ni < 4; ++ni) bR[ni] = *(const bf16x8*)(bBk[kk] + ni*2048); \
      __builtin_amdgcn_s_setprio(1); \
      _Pragma("unroll") \
      for (int mi = 0; mi < 4; ++mi) \
        _Pragma("unroll") \
        for (int ni = 0; ni < 4; ++ni) \
          acc[mi][ni] = __builtin_amdgcn_mfma_f32_16x16x32_bf16( \
              aR[mi], bR[ni], acc[mi][ni], 0, 0, 0); \
      __builtin_amdgcn_s_setprio(0); \
    } \
    BAR(); \
  } while(0)

__global__ __launch_bounds__(256, 4) void k_gemm1(const ushort_t* __restrict__ xb,
                                                  const ushort_t* __restrict__ w1t,
                                                  const ushort_t* __restrict__ w2t,
                                                  const float* __restrict__ b1,
                                                  ushort_t* __restrict__ pbuf)
{
  __shared__ ushort_t lds[16384];   // 32 KiB
  const int t = threadIdx.x;        // 0..255
  const int lane = t & 63;
  const int wid = t >> 6;           // 4 waves: 2x2, wave tile 64x64
  const int wm = wid >> 1, wn = wid & 1;
  const int lr = lane & 15, lg = lane >> 4;

  // XCD-aware swizzle (nwg=4096, %8==0 -> bijective). 512 blocks/XCD chunk.
  const int bid = blockIdx.x;
  const int swz = (bid & 7) * 512 + (bid >> 3);
  const int brow = (swz >> 4) << 7;   // 256 row tiles of 128
  const int bcol = (swz & 15) << 7;   // 16 col tiles of 128
  const int cb   = swz & 15;

  // invariant staging addresses: 4 A rows + 4 B rows per thread, pre-swizzled source col
  const ushort_t* gA[4];
  const ushort_t* gB[4];
  #pragma unroll
  for (int s = 0; s < 4; ++s){
    const int sr = s*32 + (t >> 3);
    const int sc = ((t & 7) ^ (sr & 7)) << 3;
    gA[s] = xb  + (size_t)(brow + sr) * D_PAD2 + sc;
    gB[s] = w1t + (size_t)(bcol + sr) * D_PAD2 + sc;
  }
  // invariant LDS destinations
  ushort_t* const lA0 = lds + 0*2048 + t*8;
  ushort_t* const lA1 = lds + 1*2048 + t*8;
  ushort_t* const lA2 = lds + 2*2048 + t*8;
  ushort_t* const lA3 = lds + 3*2048 + t*8;
  ushort_t* const lB0 = lds + 8192 + 0*2048 + t*8;
  ushort_t* const lB1 = lds + 8192 + 1*2048 + t*8;
  ushort_t* const lB2 = lds + 8192 + 2*2048 + t*8;
  ushort_t* const lB3 = lds + 8192 + 3*2048 + t*8;

  // fragment read bases (chunk XOR folded; rows are 64 ushort = 128 B)
  const int axor = lr & 7;
  const char* aBk[2];
  const char* bBk[2];
  aBk[0] = (const char*)lds + (wm*64 + lr)*128 + (((0 + lg) ^ axor) << 4);
  aBk[1] = (const char*)lds + (wm*64 + lr)*128 + (((4 + lg) ^ axor) << 4);
  bBk[0] = (const char*)lds + 16384 + (wn*64 + lr)*128 + (((0 + lg) ^ axor) << 4);
  bBk[1] = (const char*)lds + 16384 + (wn*64 + lr)*128 + (((4 + lg) ^ axor) << 4);

  f32x4 acc[4][4] = {};

  KSTEP(0);  KSTEP(1);  KSTEP(2);  KSTEP(3);  KSTEP(4);  KSTEP(5);
  KSTEP(6);  KSTEP(7);  KSTEP(8);  KSTEP(9);  KSTEP(10); KSTEP(11);
  KSTEP(12); KSTEP(13); KSTEP(14); KSTEP(15); KSTEP(16);

  // ---- fused epilogue: silu -> LDS h-tile [128][128] -> mini-GEMM vs W2 chunk ----
  float b1v[4];
  #pragma unroll
  for (int ni = 0; ni < 4; ++ni) b1v[ni] = b1[bcol + wn*64 + ni*16 + lr];

  #pragma unroll
  for (int mi = 0; mi < 4; ++mi){
    #pragma unroll
    for (int ni = 0; ni < 4; ++ni){
      const int col = wn*64 + ni*16 + lr;
      #pragma unroll
      for (int i2 = 0; i2 < 4; ++i2){
        const int row = wm*64 + mi*16 + lg*4 + i2;
        float v = acc[mi][ni][i2] + b1v[ni];
        float s = v / (1.0f + __expf(-v));     // silu
        const int c = col >> 3;                 // 0..15
        lds[row*128 + ((c ^ (row & 7)) << 3) + (col & 7)] = f2bf(s);
      }
    }
  }
  BAR();

  // mini-GEMM: partial[r][n] = hTile[r][:128] @ W2chunk[:128][n], n in [0,64)
  // W2 fragments in two [2][4] batches (32 regs each) to respect the 128-reg budget.
  const int rb = wid * 32;
  f32x4 acc2[2][4] = {};
  #pragma unroll
  for (int half = 0; half < 2; ++half){
    bf16x8 w2f[2][4];
    #pragma unroll
    for (int ks = 0; ks < 2; ++ks)
      #pragma unroll
      for (int ni = 0; ni < 4; ++ni)
        w2f[ks][ni] = *(const bf16x8*)(w2t + (size_t)(ni*16 + lr) * HID + bcol + (half*2+ks)*32 + lg*8);
    #pragma unroll
    for (int ks = 0; ks < 2; ++ks){
      const int kss = half*2 + ks;
      bf16x8 a2[2];
      #pragma unroll
      for (int m = 0; m < 2; ++m){
        const int row = rb + m*16 + lr;
        const int c = kss*4 + lg;
        a2[m] = *(const bf16x8*)(lds + row*128 + ((c ^ (row & 7)) << 3));
      }
      #pragma unroll
      for (int m = 0; m < 2; ++m)
        #pragma unroll
        for (int ni = 0; ni < 4; ++ni)
          acc2[m][ni] = __builtin_amdgcn_mfma_f32_16x16x32_bf16(
              a2[m], w2f[ks][ni], acc2[m][ni], 0, 0, 0);
    }
  }

  // store bf16 partials: pbuf[cb][row][col]  (rows contiguous 128 B)
  #pragma unroll
  for (int m = 0; m < 2; ++m)
    #pragma unroll
    for (int ni = 0; ni < 4; ++ni)
      #pragma unroll
      for (int i2 = 0; i2 < 4; ++i2){
        const int r = brow + rb + m*16 + lg*4 + i2;
        pbuf[((size_t)cb << 21) + ((size_t)r << 6) + ni*16 + lr] = f2bf(acc2[m][ni][i2]);
      }
}

// ---------------- reduce: sum 16 bf16 partials + b2 -> log-softmax -> NLL ----------------
__global__ __launch_bounds__(256) void k_red(const ushort_t* __restrict__ pbuf,
                                             const float* __restrict__ b2,
                                             const int* __restrict__ tgt,
                                             float* __restrict__ loss)
{
  const int lane = threadIdx.x & 63, w = threadIdx.x >> 6;
  const int row0 = blockIdx.x * 128 + w * 32;
  const float bias = (lane < 37) ? b2[lane] : 0.0f;
  for (int i = 0; i < 32; ++i){
    const int r = row0 + i;
    float s = 0.0f;
    #pragma unroll
    for (int cbk = 0; cbk < 16; ++cbk)
      s += bf2f(pbuf[((size_t)cbk << 21) + ((size_t)r << 6) + lane]);
    float x = (lane < 37) ? (s + bias) : -1e30f;
    float m = x;
    #pragma unroll
    for (int off = 1; off < 64; off <<= 1) m = fmaxf(m, __shfl_xor(m, off, 64));
    float e = __expf(x - m);
    float se = e;
    #pragma unroll
    for (int off = 1; off < 64; off <<= 1) se += __shfl_xor(se, off, 64);
    const int tg = tgt[r];
    const float pick = __shfl(x, tg, 64);
    if (lane == 0) loss[r] = m + __logf(se) - pick;
  }
}

// ---------------- launch ----------------
extern "C" void kernel_launch(void* const* d_in, const int* in_sizes, int n_in,
                              void* d_out, int out_size, void* d_ws, size_t ws_size,
                              hipStream_t stream)
{
  (void)in_sizes; (void)n_in; (void)out_size; (void)ws_size;
  const float* fc  = (const float*)d_in[0];
  const float* cam = (const float*)d_in[1];
  const float* ru  = (const float*)d_in[2];
  const float* W1  = (const float*)d_in[3];
  const float* b1  = (const float*)d_in[4];
  const float* W2  = (const float*)d_in[5];
  const float* b2  = (const float*)d_in[6];
  const int* afb = (const int*)d_in[7];
  const int* alr = (const int*)d_in[8];
  const int* ajp = (const int*)d_in[9];
  const int* ass = (const int*)d_in[10];
  const int* aat = (const int*)d_in[11];
  float* loss = (float*)d_out;

  // workspace layout (bytes):
  // xb   : 32768 x 1088 bf16   = 71,303,168
  // w1t  : 2048 x 1088 bf16    =  4,456,448
  // w2t  : 64 x 2048 bf16      =    262,144
  // tgt  : 32768 int32         =    131,072
  // pbuf : 16 x 32768 x 64 bf16= 67,108,864   (total ~136.6 MiB)
  char* ws = (char*)d_ws;
  unsigned short* xb  = (unsigned short*)(ws);
  unsigned short* w1t = (unsigned short*)(ws + 71303168);
  unsigned short* w2t = (unsigned short*)(ws + 75759616);
  int*            tgt = (int*)           (ws + 76021760);
  unsigned short* pbuf= (unsigned short*)(ws + 76152832);

  // fused prep: fc(2048 x8 grid-stride) + w1t-transpose(544) + w2t(512) + disc(128)
  k_prep<<<3232, 256, 0, stream>>>(fc, W1, W2, cam, ru, afb, alr, ajp, ass, aat,
                                   xb, w1t, w2t, tgt);
  k_gemm1<<<(B_ROWS/128) * (HID/128), 256, 0, stream>>>(xb, w1t, w2t, b1, pbuf);
  k_red  <<<B_ROWS / 128, 256, 0, stream>>>(pbuf, b2, tgt, loss);
}

// Round 18
// 253.151 us; speedup vs baseline: 4.9536x; 1.0014x over previous
//
#include <hip/hip_runtime.h>
#include <hip/hip_bf16.h>
#include <stdint.h>

// Problem constants
#define B_ROWS 32768
#define NUM_IN 1024
#define D_PAD2 1088   // 1064 padded to 17*64 K-tiles
#define HID    2048
#define NPAD   64     // 37 logits padded to 64

typedef __attribute__((ext_vector_type(8))) short bf16x8;
typedef __attribute__((ext_vector_type(4))) float f32x4;
typedef unsigned short ushort_t;

__device__ __forceinline__ unsigned short f2bf(float f){
  union { float f; uint32_t u; } x; x.f = f;
  uint32_t u = x.u;
  return (unsigned short)((u + 0x7FFFu + ((u >> 16) & 1u)) >> 16);
}

__device__ __forceinline__ float bf2f(unsigned short u){
  union { uint32_t u; float f; } x; x.u = ((uint32_t)u) << 16;
  return x.f;
}

// ---------------- discretizer scan (per batch element) ----------------
__device__ __forceinline__ int disc_step(
    float cam0, float cam1, const int a[5],
    float& ac0, float& ac1, float& delta,
    int r[5], bool& dch, int& cam_steps, bool& committed, float& norm)
{
  const int RS[5] = {6, 8, 10, 11, 14};
  norm += committed ? 0.0f : 1.0f;
  bool commit = ((fabsf(cam0) < 1e-5f) && (fabsf(cam1) < 1e-5f)) || (cam_steps >= 6);
  #pragma unroll
  for (int i = 0; i < 5; ++i) commit = commit && (r[i] == a[i]);
  int dac = 0;
  bool modified = commit;
  #pragma unroll
  for (int i = 0; i < 5; ++i){
    bool disc = (!modified) && (r[i] != a[i]);
    if (disc){
      dac = (a[i] == 0) ? (r[i] - 1 + RS[i]) : (a[i] - 1 + RS[i]);
      r[i] = a[i];
      modified = true;
    }
  }
  float d2 = delta * 2.0f;
  // NOTE: reference compares BOTH cam0 and cam1 against ac[:,0] — replicate.
  bool dmask = (!modified) && (!dch) &&
               ((fabsf(cam0 - ac0) > d2) || (fabsf(cam1 - ac0) > d2));
  if (dmask){ dac = 5; delta = fminf(d2, 0.5f); modified = true; }
  if (!modified){
    float sx = (cam0 < ac0) ? -1.0f : 1.0f;
    float sy = (cam1 < ac1) ? -1.0f : 1.0f;
    dac = (sx < 0.0f) ? ((sy < 0.0f) ? 1 : 3) : ((sy < 0.0f) ? 2 : 4);
    ac0 += sx * delta; ac1 += sy * delta;
    delta *= 0.5f;
    dch = true;
    cam_steps += 1;
  }
  committed = committed || commit;
  return dac;
}

// ---------------- fused prep: fc convert (grid-stride) | W1^T | W2^T | disc ----------------
// block ranges: [0,2048) fc x8 ; [2048,2592) w1t-transpose ; [2592,3104) w2t ; [3104,3232) disc
__global__ void k_prep(const float* __restrict__ fc, const float* __restrict__ W1,
                       const float* __restrict__ W2,
                       const float* __restrict__ camera, const float* __restrict__ rand_u,
                       const int* __restrict__ afb, const int* __restrict__ alr,
                       const int* __restrict__ ajp, const int* __restrict__ ass,
                       const int* __restrict__ aat,
                       unsigned short* __restrict__ xb, unsigned short* __restrict__ w1t,
                       unsigned short* __restrict__ w2t, int* __restrict__ tgt)
{
  __shared__ float lt[64][65];      // transpose tile (+1 pad, conflict-free)
  const int b = blockIdx.x;
  const int tid = threadIdx.x;
  if (b < 2048){
    // fc f32 -> bf16, grid-stride over 16384 logical blocks
    #pragma unroll
    for (int it = 0; it < 8; ++it){
      int gid = (b + it * 2048) * 256 + tid;
      int row = gid >> 7;
      int c   = gid & 127;
      const float4* p = (const float4*)(fc + (size_t)row * NUM_IN + c * 8);
      float4 f0 = p[0], f1 = p[1];
      uint4 pk;
      pk.x = (uint32_t)f2bf(f0.x) | ((uint32_t)f2bf(f0.y) << 16);
      pk.y = (uint32_t)f2bf(f0.z) | ((uint32_t)f2bf(f0.w) << 16);
      pk.z = (uint32_t)f2bf(f1.x) | ((uint32_t)f2bf(f1.y) << 16);
      pk.w = (uint32_t)f2bf(f1.z) | ((uint32_t)f2bf(f1.w) << 16);
      *(uint4*)(xb + (size_t)row * D_PAD2 + c * 8) = pk;
    }
    return;
  }
  if (b < 2592){
    // W1 [1064][2048] -> w1t [2048][1088] via 64x64 LDS tile; coalesced both sides
    const int bi = b - 2048;
    const int kt = bi % 17, nt = bi / 17;
    const int k0 = kt * 64, n0 = nt * 64;
    const int c = tid & 63, rq = tid >> 6;
    #pragma unroll
    for (int rr = 0; rr < 16; ++rr){
      const int r = rr * 4 + rq;
      const int k = k0 + r;
      lt[r][c] = (k < 1064) ? W1[(size_t)k * HID + n0 + c] : 0.0f;
    }
    __syncthreads();
    #pragma unroll
    for (int rr = 0; rr < 16; ++rr){
      const int r = rr * 4 + rq;
      w1t[(size_t)(n0 + r) * D_PAD2 + k0 + c] = f2bf(lt[c][r]);
    }
    return;
  }
  if (b < 3104){
    int idx = (b - 2592) * 256 + tid;
    int n = idx >> 11;
    int k = idx & (HID - 1);
    float v = (n < 37) ? W2[(size_t)k * 37 + n] : 0.0f;
    w2t[idx] = f2bf(v);
    return;
  }
  // discretizer
  int row = (b - 3104) * 256 + tid;
  float cam0 = camera[2*row], cam1 = camera[2*row + 1];
  int a[5] = { afb[row], alr[row], ajp[row], ass[row], aat[row] };

  float ac0 = 0.f, ac1 = 0.f, delta = 0.0625f, norm = 0.f;
  int r[5] = {0,0,0,0,0};
  bool dch = false, committed = false; int cam_steps = 0;
  for (int t = 0; t < 20; ++t)
    disc_step(cam0, cam1, a, ac0, ac1, delta, r, dch, cam_steps, committed, norm);

  int rs = (int)(rand_u[row] * norm);
  if (rs > 19) rs = 19;
  if (rs < 0) rs = 0;

  ac0 = 0.f; ac1 = 0.f; delta = 0.0625f; norm = 0.f;
  r[0]=r[1]=r[2]=r[3]=r[4]=0; dch = false; committed = false; cam_steps = 0;
  for (int t = 0; t < rs; ++t)
    disc_step(cam0, cam1, a, ac0, ac1, delta, r, dch, cam_steps, committed, norm);

  float vec[40];
  #pragma unroll
  for (int j = 0; j < 40; ++j) vec[j] = 0.0f;
  vec[0] = ac0; vec[1] = ac1;
  const int offs[5] = {2, 5, 8, 10, 14};
  #pragma unroll
  for (int i = 0; i < 5; ++i) vec[offs[i] + r[i]] = 1.0f;
  vec[38] = delta; vec[39] = dch ? 1.0f : 0.0f;

  int dac = disc_step(cam0, cam1, a, ac0, ac1, delta, r, dch, cam_steps, committed, norm);
  tgt[row] = dac;

  unsigned short* o = xb + (size_t)row * D_PAD2 + NUM_IN;
  #pragma unroll
  for (int j = 0; j < 40; ++j) o[j] = f2bf(vec[j]);
  #pragma unroll
  for (int j = 40; j < 64; ++j) o[j] = 0;
}

// ---------------- GEMM1: 128x128, 4 waves, 4 blocks/CU, unrolled K (compiler-folded imm) ----------------
// LDS 32 KB: A [128][64] at ushort 0, B [128][64] at ushort 8192. Epilogue: h [128][128].
// Staging: invariant base pointers + compile-time constant displacement (KT*64 ushorts);
// builtin offset arg ALWAYS 0 (round-15 lesson: nonzero offset arg corrupts staging).
// K-loop MFMA shape stays 16x16x32 (round-17 lesson: 32x32 A/B frag layout unverified -> NaN).

#define BAR() __syncthreads()

#define GL16(G, L) __builtin_amdgcn_global_load_lds( \
    (const __attribute__((address_space(1))) void*)(G), \
    (__attribute__((address_space(3))) void*)(L), 16, 0, 0)

// one K-step: stage tile KT (A+B, 8 loads, const-folded displacement), sync,
// kk-split frags + 32 MFMA, sync
#define KSTEP(KT) do { \
    GL16(gA[0] + (KT)*64, lA0); GL16(gA[1] + (KT)*64, lA1); \
    GL16(gA[2] + (KT)*64, lA2); GL16(gA[3] + (KT)*64, lA3); \
    GL16(gB[0] + (KT)*64, lB0); GL16(gB[1] + (KT)*64, lB1); \
    GL16(gB[2] + (KT)*64, lB2); GL16(gB[3] + (KT)*64, lB3); \
    BAR(); \
    _Pragma("unroll") \
    for (int kk = 0; kk < 2; ++kk){ \
      bf16x8 aR[4], bR[4]; \
      _Pragma("unroll") \
      for (int mi = 0; mi < 4; ++mi) aR[mi] = *(const bf16x8*)(aBk[kk] + mi*2048); \
      _Pragma("unroll") \
      for (int ni = 0; ni < 4; ++ni) bR[ni] = *(const bf16x8*)(bBk[kk] + ni*2048); \
      __builtin_amdgcn_s_setprio(1); \
      _Pragma("unroll") \
      for (int mi = 0; mi < 4; ++mi) \
        _Pragma("unroll") \
        for (int ni = 0; ni < 4; ++ni) \
          acc[mi][ni] = __builtin_amdgcn_mfma_f32_16x16x32_bf16( \
              aR[mi], bR[ni], acc[mi][ni], 0, 0, 0); \
      __builtin_amdgcn_s_setprio(0); \
    } \
    BAR(); \
  } while(0)

__global__ __launch_bounds__(256, 4) void k_gemm1(const ushort_t* __restrict__ xb,
                                                  const ushort_t* __restrict__ w1t,
                                                  const ushort_t* __restrict__ w2t,
                                                  const float* __restrict__ b1,
                                                  ushort_t* __restrict__ pbuf)
{
  __shared__ ushort_t lds[16384];   // 32 KiB
  const int t = threadIdx.x;        // 0..255
  const int lane = t & 63;
  const int wid = t >> 6;           // 4 waves: 2x2, wave tile 64x64
  const int wm = wid >> 1, wn = wid & 1;
  const int lr = lane & 15, lg = lane >> 4;

  // XCD-aware swizzle (nwg=4096, %8==0 -> bijective). 512 blocks/XCD chunk.
  const int bid = blockIdx.x;
  const int swz = (bid & 7) * 512 + (bid >> 3);
  const int brow = (swz >> 4) << 7;   // 256 row tiles of 128
  const int bcol = (swz & 15) << 7;   // 16 col tiles of 128
  const int cb   = swz & 15;

  // invariant staging addresses: 4 A rows + 4 B rows per thread, pre-swizzled source col
  const ushort_t* gA[4];
  const ushort_t* gB[4];
  #pragma unroll
  for (int s = 0; s < 4; ++s){
    const int sr = s*32 + (t >> 3);
    const int sc = ((t & 7) ^ (sr & 7)) << 3;
    gA[s] = xb  + (size_t)(brow + sr) * D_PAD2 + sc;
    gB[s] = w1t + (size_t)(bcol + sr) * D_PAD2 + sc;
  }
  // invariant LDS destinations
  ushort_t* const lA0 = lds + 0*2048 + t*8;
  ushort_t* const lA1 = lds + 1*2048 + t*8;
  ushort_t* const lA2 = lds + 2*2048 + t*8;
  ushort_t* const lA3 = lds + 3*2048 + t*8;
  ushort_t* const lB0 = lds + 8192 + 0*2048 + t*8;
  ushort_t* const lB1 = lds + 8192 + 1*2048 + t*8;
  ushort_t* const lB2 = lds + 8192 + 2*2048 + t*8;
  ushort_t* const lB3 = lds + 8192 + 3*2048 + t*8;

  // fragment read bases (chunk XOR folded; rows are 64 ushort = 128 B)
  const int axor = lr & 7;
  const char* aBk[2];
  const char* bBk[2];
  aBk[0] = (const char*)lds + (wm*64 + lr)*128 + (((0 + lg) ^ axor) << 4);
  aBk[1] = (const char*)lds + (wm*64 + lr)*128 + (((4 + lg) ^ axor) << 4);
  bBk[0] = (const char*)lds + 16384 + (wn*64 + lr)*128 + (((0 + lg) ^ axor) << 4);
  bBk[1] = (const char*)lds + 16384 + (wn*64 + lr)*128 + (((4 + lg) ^ axor) << 4);

  f32x4 acc[4][4] = {};

  KSTEP(0);  KSTEP(1);  KSTEP(2);  KSTEP(3);  KSTEP(4);  KSTEP(5);
  KSTEP(6);  KSTEP(7);  KSTEP(8);  KSTEP(9);  KSTEP(10); KSTEP(11);
  KSTEP(12); KSTEP(13); KSTEP(14); KSTEP(15); KSTEP(16);

  // ---- fused epilogue: silu -> LDS h-tile [128][128] -> mini-GEMM vs W2 chunk ----
  float b1v[4];
  #pragma unroll
  for (int ni = 0; ni < 4; ++ni) b1v[ni] = b1[bcol + wn*64 + ni*16 + lr];

  #pragma unroll
  for (int mi = 0; mi < 4; ++mi){
    #pragma unroll
    for (int ni = 0; ni < 4; ++ni){
      const int col = wn*64 + ni*16 + lr;
      #pragma unroll
      for (int i2 = 0; i2 < 4; ++i2){
        const int row = wm*64 + mi*16 + lg*4 + i2;
        float v = acc[mi][ni][i2] + b1v[ni];
        float s = v / (1.0f + __expf(-v));     // silu
        const int c = col >> 3;                 // 0..15
        lds[row*128 + ((c ^ (row & 7)) << 3) + (col & 7)] = f2bf(s);
      }
    }
  }
  BAR();

  // mini-GEMM: partial[r][n] = hTile[r][:128] @ W2chunk[:128][n], n in [0,64)
  // W2 fragments in two [2][4] batches (32 regs each) to respect the 128-reg budget.
  const int rb = wid * 32;
  f32x4 acc2[2][4] = {};
  #pragma unroll
  for (int half = 0; half < 2; ++half){
    bf16x8 w2f[2][4];
    #pragma unroll
    for (int ks = 0; ks < 2; ++ks)
      #pragma unroll
      for (int ni = 0; ni < 4; ++ni)
        w2f[ks][ni] = *(const bf16x8*)(w2t + (size_t)(ni*16 + lr) * HID + bcol + (half*2+ks)*32 + lg*8);
    #pragma unroll
    for (int ks = 0; ks < 2; ++ks){
      const int kss = half*2 + ks;
      bf16x8 a2[2];
      #pragma unroll
      for (int m = 0; m < 2; ++m){
        const int row = rb + m*16 + lr;
        const int c = kss*4 + lg;
        a2[m] = *(const bf16x8*)(lds + row*128 + ((c ^ (row & 7)) << 3));
      }
      #pragma unroll
      for (int m = 0; m < 2; ++m)
        #pragma unroll
        for (int ni = 0; ni < 4; ++ni)
          acc2[m][ni] = __builtin_amdgcn_mfma_f32_16x16x32_bf16(
              a2[m], w2f[ks][ni], acc2[m][ni], 0, 0, 0);
    }
  }

  // store bf16 partials: pbuf[cb][row][col]  (rows contiguous 128 B)
  #pragma unroll
  for (int m = 0; m < 2; ++m)
    #pragma unroll
    for (int ni = 0; ni < 4; ++ni)
      #pragma unroll
      for (int i2 = 0; i2 < 4; ++i2){
        const int r = brow + rb + m*16 + lg*4 + i2;
        pbuf[((size_t)cb << 21) + ((size_t)r << 6) + ni*16 + lr] = f2bf(acc2[m][ni][i2]);
      }
}

// ---------------- reduce: sum 16 bf16 partials + b2 -> log-softmax -> NLL ----------------
__global__ __launch_bounds__(256) void k_red(const ushort_t* __restrict__ pbuf,
                                             const float* __restrict__ b2,
                                             const int* __restrict__ tgt,
                                             float* __restrict__ loss)
{
  const int lane = threadIdx.x & 63, w = threadIdx.x >> 6;
  const int row0 = blockIdx.x * 128 + w * 32;
  const float bias = (lane < 37) ? b2[lane] : 0.0f;
  for (int i = 0; i < 32; ++i){
    const int r = row0 + i;
    float s = 0.0f;
    #pragma unroll
    for (int cbk = 0; cbk < 16; ++cbk)
      s += bf2f(pbuf[((size_t)cbk << 21) + ((size_t)r << 6) + lane]);
    float x = (lane < 37) ? (s + bias) : -1e30f;
    float m = x;
    #pragma unroll
    for (int off = 1; off < 64; off <<= 1) m = fmaxf(m, __shfl_xor(m, off, 64));
    float e = __expf(x - m);
    float se = e;
    #pragma unroll
    for (int off = 1; off < 64; off <<= 1) se += __shfl_xor(se, off, 64);
    const int tg = tgt[r];
    const float pick = __shfl(x, tg, 64);
    if (lane == 0) loss[r] = m + __logf(se) - pick;
  }
}

// ---------------- launch ----------------
extern "C" void kernel_launch(void* const* d_in, const int* in_sizes, int n_in,
                              void* d_out, int out_size, void* d_ws, size_t ws_size,
                              hipStream_t stream)
{
  (void)in_sizes; (void)n_in; (void)out_size; (void)ws_size;
  const float* fc  = (const float*)d_in[0];
  const float* cam = (const float*)d_in[1];
  const float* ru  = (const float*)d_in[2];
  const float* W1  = (const float*)d_in[3];
  const float* b1  = (const float*)d_in[4];
  const float* W2  = (const float*)d_in[5];
  const float* b2  = (const float*)d_in[6];
  const int* afb = (const int*)d_in[7];
  const int* alr = (const int*)d_in[8];
  const int* ajp = (const int*)d_in[9];
  const int* ass = (const int*)d_in[10];
  const int* aat = (const int*)d_in[11];
  float* loss = (float*)d_out;

  // workspace layout (bytes):
  // xb   : 32768 x 1088 bf16   = 71,303,168
  // w1t  : 2048 x 1088 bf16    =  4,456,448
  // w2t  : 64 x 2048 bf16      =    262,144
  // tgt  : 32768 int32         =    131,072
  // pbuf : 16 x 32768 x 64 bf16= 67,108,864   (total ~136.6 MiB)
  char* ws = (char*)d_ws;
  unsigned short* xb  = (unsigned short*)(ws);
  unsigned short* w1t = (unsigned short*)(ws + 71303168);
  unsigned short* w2t = (unsigned short*)(ws + 75759616);
  int*            tgt = (int*)           (ws + 76021760);
  unsigned short* pbuf= (unsigned short*)(ws + 76152832);

  // fused prep: fc(2048 x8 grid-stride) + w1t-transpose(544) + w2t(512) + disc(128)
  k_prep<<<3232, 256, 0, stream>>>(fc, W1, W2, cam, ru, afb, alr, ajp, ass, aat,
                                   xb, w1t, w2t, tgt);
  k_gemm1<<<(B_ROWS/128) * (HID/128), 256, 0, stream>>>(xb, w1t, w2t, b1, pbuf);
  k_red  <<<B_ROWS / 128, 256, 0, stream>>>(pbuf, b2, tgt, loss);
}